// Round 4
// baseline (2094.677 us; speedup 1.0000x reference)
//
#include <hip/hip_runtime.h>
#include <hip/hip_bf16.h>

typedef short short8 __attribute__((ext_vector_type(8)));
typedef float f32x4 __attribute__((ext_vector_type(4)));
typedef unsigned long long u64;
typedef unsigned u32;

constexpr int S = 256, B = 64, IN = 512, H = 1024;
constexpr int M = S * B;        // 16384
constexpr int NG = 4 * H;       // 4096

// ---------------- prep: fp32 -> bf16 ----------------
__global__ void f2b(const float* __restrict__ s, __hip_bfloat16* __restrict__ d, int n4) {
  int i = blockIdx.x * blockDim.x + threadIdx.x;
  if (i >= n4) return;
  float4 v = reinterpret_cast<const float4*>(s)[i];
  __hip_bfloat16 o[4] = {__float2bfloat16(v.x), __float2bfloat16(v.y),
                         __float2bfloat16(v.z), __float2bfloat16(v.w)};
  *reinterpret_cast<uint2*>(d + 4 * (size_t)i) = *reinterpret_cast<uint2*>(o);
}

__global__ void bias_k(const float* bx0, const float* bx1, const float* bx2, const float* bx3,
                       const float* bh0, const float* bh1, const float* bh2, const float* bh3,
                       float* bias) {
  int i = blockIdx.x * blockDim.x + threadIdx.x;
  if (i >= NG) return;
  int g = i >> 10, j = i & 1023;
  const float* bx = g == 0 ? bx0 : g == 1 ? bx1 : g == 2 ? bx2 : bx3;
  const float* bh = g == 0 ? bh0 : g == 1 ? bh1 : g == 2 ? bh2 : bh3;
  bias[i] = bx[j] + bh[j];
}

// ---------------- gx = x @ Wx^T + bias : m97-structure 128x128 tile ----------------
// LDS layout [kseg][row][8 bf16] so global_load_lds dest is linear and
// frag ds_read_b128 is only 2-way bank-aliased (free).
__global__ __launch_bounds__(256) void gx_gemm(const __hip_bfloat16* __restrict__ xb,
                                               const __hip_bfloat16* __restrict__ wxb,
                                               const float* __restrict__ bias,
                                               __hip_bfloat16* __restrict__ gx) {
  __shared__ __align__(16) ushort As[4][128][8];   // 8 KB
  __shared__ __align__(16) ushort Bs[4][128][8];   // 8 KB
  const int tid = threadIdx.x;
  const int l = tid & 63, w = tid >> 6;
  const int m0 = blockIdx.y * 128, n0 = blockIdx.x * 128;
  const int wm = (w >> 1) * 64, wn = (w & 1) * 64;
  const int cr = l & 15, kg = l >> 4;
  f32x4 acc[4][4] = {};

  ushort* Af = &As[0][0][0];
  ushort* Bfl = &Bs[0][0][0];

  for (int k0 = 0; k0 < IN; k0 += 32) {
    __syncthreads();
#pragma unroll
    for (int n = 0; n < 2; ++n) {
      int cA = w * 2 + n;            // chunk 0..7 (1 KB each)
      int f = cA * 64 + l;           // flat 16B-unit index: seg=f>>7, row=f&127
      const __hip_bfloat16* ga = xb + (size_t)(m0 + (f & 127)) * IN + k0 + (f >> 7) * 8;
      const __hip_bfloat16* gb = wxb + (size_t)(n0 + (f & 127)) * IN + k0 + (f >> 7) * 8;
      __builtin_amdgcn_global_load_lds((const u32*)ga, (u32*)(Af + cA * 512), 16, 0, 0);
      __builtin_amdgcn_global_load_lds((const u32*)gb, (u32*)(Bfl + cA * 512), 16, 0, 0);
    }
    __syncthreads();
    short8 a[4], b[4];
#pragma unroll
    for (int mi = 0; mi < 4; ++mi)
      a[mi] = *reinterpret_cast<const short8*>(&As[kg][wm + mi * 16 + cr][0]);
#pragma unroll
    for (int ni = 0; ni < 4; ++ni)
      b[ni] = *reinterpret_cast<const short8*>(&Bs[kg][wn + ni * 16 + cr][0]);
#pragma unroll
    for (int mi = 0; mi < 4; ++mi)
#pragma unroll
      for (int ni = 0; ni < 4; ++ni)
        acc[mi][ni] = __builtin_amdgcn_mfma_f32_16x16x32_bf16(a[mi], b[ni], acc[mi][ni], 0, 0, 0);
  }

#pragma unroll
  for (int ni = 0; ni < 4; ++ni) {
    int n = n0 + wn + ni * 16 + cr;
    float bv = bias[n];
#pragma unroll
    for (int mi = 0; mi < 4; ++mi) {
#pragma unroll
      for (int r = 0; r < 4; ++r) {
        int m = m0 + wm + mi * 16 + kg * 4 + r;
        gx[(size_t)m * NG + n] = __float2bfloat16(acc[mi][ni][r] + bv);
      }
    }
  }
}

__device__ __forceinline__ u64 ldq(const u64* p) {
  return __hip_atomic_load(p, __ATOMIC_RELAXED, __HIP_MEMORY_SCOPE_AGENT);
}
__device__ __forceinline__ void stw(u32* p, u32 v) {
  __hip_atomic_store(p, v, __ATOMIC_RELAXED, __HIP_MEMORY_SCOPE_AGENT);
}
__device__ __forceinline__ float sigm(float x) {
  return __builtin_amdgcn_rcpf(1.f + __expf(-x));
}
__device__ __forceinline__ float tanhfast(float x) {
  return 2.f * __builtin_amdgcn_rcpf(1.f + __expf(-2.f * x)) - 1.f;
}

// ---------------- persistent recurrence: tagged-dataflow h exchange ----------------
// h word = (bf16(h) << 16) | step_tag. No flags, no fences, no barriers:
// consumers poll the data words themselves (relaxed agent sc1). Ping-pong (2 bufs)
// makes it WAR-safe by dataflow within each batch-group; bgs are independent.
__global__ __launch_bounds__(256, 1) void lstm_rec(const __hip_bfloat16* __restrict__ whb,
                                                   const __hip_bfloat16* __restrict__ gx,
                                                   u32* __restrict__ hx,
                                                   float* __restrict__ out) {
  __shared__ __align__(16) ushort Bf[4][32][64][8];   // 128 KB: Wh slice, B-frag order
  __shared__ __align__(16) float gt[4][4][16][20];
  const int tid = threadIdx.x;
  const int l = tid & 63, w = tid >> 6;
  const int jg = blockIdx.x >> 2, bg = blockIdx.x & 3;
  const int j0 = jg * 16, b0 = bg * 16;

  for (int idx = tid; idx < 4 * 32 * 64; idx += 256) {
    int g = idx >> 11, kb = (idx >> 6) & 31, ll = idx & 63;
    const __hip_bfloat16* src =
        whb + ((size_t)(g * H + j0 + (ll & 15))) * H + kb * 32 + (ll >> 4) * 8;
    *reinterpret_cast<uint4*>(&Bf[g][kb][ll][0]) = *reinterpret_cast<const uint4*>(src);
  }
  __syncthreads();

  const int cr = l & 15, kg = l >> 4;
  const int kb0 = w * 8;
  const int bi = tid >> 4, j = tid & 15;
  float c = 0.f;

  for (int t = 0; t < S; ++t) {
    const u32* hsrc = hx + (size_t)(t & 1) * (B * H);
    u32* hdst = hx + (size_t)((t + 1) & 1) * (B * H);

    // gx prefetch (plain cached loads; independent of h)
    const __hip_bfloat16* gxr = gx + (size_t)(t * B + b0 + bi) * NG + j0 + j;
    ushort q0 = *(const ushort*)&gxr[0 * H];
    ushort q1 = *(const ushort*)&gxr[1 * H];
    ushort q2 = *(const ushort*)&gxr[2 * H];
    ushort q3 = *(const ushort*)&gxr[3 * H];

    // load this thread's 64 h words (8 per MFMA k-chunk), tag-validated
    const u32* hp = hsrc + (size_t)(b0 + cr) * H + w * 256 + kg * 8;
    const u64 tagpat = (u64)(u32)t | ((u64)(u32)t << 32);
    u64 q[32];
#pragma unroll
    for (int kk = 0; kk < 8; ++kk) {
      const u64* p = reinterpret_cast<const u64*>(hp + kk * 32);
      q[kk * 4 + 0] = ldq(p + 0);
      q[kk * 4 + 1] = ldq(p + 1);
      q[kk * 4 + 2] = ldq(p + 2);
      q[kk * 4 + 3] = ldq(p + 3);
    }
#pragma unroll
    for (int r = 0; r < 32; ++r) {
      const u64* p = reinterpret_cast<const u64*>(hp + (r >> 2) * 32) + (r & 3);
      while (((q[r] ^ tagpat) & 0x0000ffff0000ffffull) != 0ull) q[r] = ldq(p);
    }

    // unpack (bf16 in high halves) + MFMA partials over this wave's K range
    f32x4 acc[4] = {};
#pragma unroll
    for (int kk = 0; kk < 8; ++kk) {
      u32 w0 = (u32)q[kk * 4 + 0], w1 = (u32)(q[kk * 4 + 0] >> 32);
      u32 w2 = (u32)q[kk * 4 + 1], w3 = (u32)(q[kk * 4 + 1] >> 32);
      u32 w4 = (u32)q[kk * 4 + 2], w5 = (u32)(q[kk * 4 + 2] >> 32);
      u32 w6 = (u32)q[kk * 4 + 3], w7 = (u32)(q[kk * 4 + 3] >> 32);
      union { u32 u[4]; short8 s; } ua;
      ua.u[0] = (w0 >> 16) | (w1 & 0xffff0000u);
      ua.u[1] = (w2 >> 16) | (w3 & 0xffff0000u);
      ua.u[2] = (w4 >> 16) | (w5 & 0xffff0000u);
      ua.u[3] = (w6 >> 16) | (w7 & 0xffff0000u);
#pragma unroll
      for (int g = 0; g < 4; ++g) {
        short8 bv = *reinterpret_cast<const short8*>(&Bf[g][kb0 + kk][l][0]);
        acc[g] = __builtin_amdgcn_mfma_f32_16x16x32_bf16(ua.s, bv, acc[g], 0, 0, 0);
      }
    }
#pragma unroll
    for (int g = 0; g < 4; ++g)
      *reinterpret_cast<f32x4*>(&gt[w][g][cr][kg * 4]) = acc[g];
    __syncthreads();

    // cross-wave K reduction + gates
    float sf = 0.f, si = 0.f, so = 0.f, sc = 0.f;
#pragma unroll
    for (int wv = 0; wv < 4; ++wv) {
      sf += gt[wv][0][j][bi];
      si += gt[wv][1][j][bi];
      so += gt[wv][2][j][bi];
      sc += gt[wv][3][j][bi];
    }
    float gf = sf + __uint_as_float((u32)q0 << 16);
    float gi = si + __uint_as_float((u32)q1 << 16);
    float go = so + __uint_as_float((u32)q2 << 16);
    float gc = sc + __uint_as_float((u32)q3 << 16);
    float f = sigm(gf);
    float i_ = sigm(gi);
    float o = sigm(go);
    float cn = f * c + i_ * tanhfast(gc);
    float hn = o * tanhfast(cn);
    c = cn;

    out[((size_t)(t * B + b0 + bi)) * H + j0 + j] = hn;
    if (t == S - 1) {
      out[(size_t)S * B * H + (size_t)(b0 + bi) * H + j0 + j] = hn;
      out[(size_t)S * B * H + (size_t)B * H + (size_t)(b0 + bi) * H + j0 + j] = cn;
    }

    // publish h_{t+1}: one self-tagged word per thread (single L3 leg)
    u32 word = ((u32)__bfloat16_as_ushort(__float2bfloat16(hn)) << 16) | (u32)(t + 1);
    stw(hdst + (size_t)(b0 + bi) * H + j0 + j, word);

    __syncthreads();  // protect gt for next iteration's writes
  }
}

extern "C" void kernel_launch(void* const* d_in, const int* in_sizes, int n_in,
                              void* d_out, int out_size, void* d_ws, size_t ws_size,
                              hipStream_t stream) {
  const float* x = (const float*)d_in[0];
  const float* Wx[4] = {(const float*)d_in[1], (const float*)d_in[3],
                        (const float*)d_in[5], (const float*)d_in[7]};
  const float* bx[4] = {(const float*)d_in[2], (const float*)d_in[4],
                        (const float*)d_in[6], (const float*)d_in[8]};
  const float* Wh[4] = {(const float*)d_in[9], (const float*)d_in[11],
                        (const float*)d_in[13], (const float*)d_in[15]};
  const float* bh[4] = {(const float*)d_in[10], (const float*)d_in[12],
                        (const float*)d_in[14], (const float*)d_in[16]};

  char* ws = (char*)d_ws;
  size_t o_hx = 0;                                    // 2*B*H f32 = 512 KB
  size_t o_bias = o_hx + (size_t)2 * B * H * 4;
  size_t o_x = o_bias + (size_t)NG * 4;
  size_t o_wx = o_x + (size_t)M * IN * 2;
  size_t o_wh = o_wx + (size_t)NG * IN * 2;
  size_t o_gx = o_wh + (size_t)NG * H * 2;

  u32* hxp = (u32*)(ws + o_hx);
  float* biasp = (float*)(ws + o_bias);
  __hip_bfloat16* xb = (__hip_bfloat16*)(ws + o_x);
  __hip_bfloat16* wxb = (__hip_bfloat16*)(ws + o_wx);
  __hip_bfloat16* whb = (__hip_bfloat16*)(ws + o_wh);
  __hip_bfloat16* gxp = (__hip_bfloat16*)(ws + o_gx);

  // zero hx: tag 0 == step 0, value 0 == h_0 (runs inside the graph every replay)
  hipMemsetAsync(ws, 0, o_bias, stream);

  f2b<<<(M * IN / 4) / 256, 256, 0, stream>>>(x, xb, M * IN / 4);
  for (int g = 0; g < 4; ++g)
    f2b<<<(H * IN / 4) / 256, 256, 0, stream>>>(Wx[g], wxb + (size_t)g * H * IN, H * IN / 4);
  for (int g = 0; g < 4; ++g)
    f2b<<<(H * H / 4) / 256, 256, 0, stream>>>(Wh[g], whb + (size_t)g * H * H, H * H / 4);
  bias_k<<<NG / 256, 256, 0, stream>>>(bx[0], bx[1], bx[2], bx[3],
                                       bh[0], bh[1], bh[2], bh[3], biasp);

  dim3 gg(NG / 128, M / 128);
  gx_gemm<<<gg, 256, 0, stream>>>(xb, wxb, biasp, gxp);

  lstm_rec<<<256, 256, 0, stream>>>(whb, gxp, hxp, (float*)d_out);
}

// Round 5
// 2017.215 us; speedup vs baseline: 1.0384x; 1.0384x over previous
//
#include <hip/hip_runtime.h>
#include <hip/hip_bf16.h>

typedef short short8 __attribute__((ext_vector_type(8)));
typedef float f32x4 __attribute__((ext_vector_type(4)));
typedef unsigned long long u64;
typedef unsigned u32;

constexpr int S = 256, B = 64, IN = 512, H = 1024;
constexpr int M = S * B;        // 16384
constexpr int NG = 4 * H;       // 4096

// ---------------- prep: fp32 -> bf16 ----------------
__global__ void f2b(const float* __restrict__ s, __hip_bfloat16* __restrict__ d, int n4) {
  int i = blockIdx.x * blockDim.x + threadIdx.x;
  if (i >= n4) return;
  float4 v = reinterpret_cast<const float4*>(s)[i];
  __hip_bfloat16 o[4] = {__float2bfloat16(v.x), __float2bfloat16(v.y),
                         __float2bfloat16(v.z), __float2bfloat16(v.w)};
  *reinterpret_cast<uint2*>(d + 4 * (size_t)i) = *reinterpret_cast<uint2*>(o);
}

__global__ void bias_k(const float* bx0, const float* bx1, const float* bx2, const float* bx3,
                       const float* bh0, const float* bh1, const float* bh2, const float* bh3,
                       float* bias) {
  int i = blockIdx.x * blockDim.x + threadIdx.x;
  if (i >= NG) return;
  int g = i >> 10, j = i & 1023;
  const float* bx = g == 0 ? bx0 : g == 1 ? bx1 : g == 2 ? bx2 : bx3;
  const float* bh = g == 0 ? bh0 : g == 1 ? bh1 : g == 2 ? bh2 : bh3;
  bias[i] = bx[j] + bh[j];
}

// ---------------- gx = x @ Wx^T + bias : m97-structure 128x128 tile ----------------
__global__ __launch_bounds__(256) void gx_gemm(const __hip_bfloat16* __restrict__ xb,
                                               const __hip_bfloat16* __restrict__ wxb,
                                               const float* __restrict__ bias,
                                               __hip_bfloat16* __restrict__ gx) {
  __shared__ __align__(16) ushort As[4][128][8];   // 8 KB
  __shared__ __align__(16) ushort Bs[4][128][8];   // 8 KB
  const int tid = threadIdx.x;
  const int l = tid & 63, w = tid >> 6;
  const int m0 = blockIdx.y * 128, n0 = blockIdx.x * 128;
  const int wm = (w >> 1) * 64, wn = (w & 1) * 64;
  const int cr = l & 15, kg = l >> 4;
  f32x4 acc[4][4] = {};

  ushort* Af = &As[0][0][0];
  ushort* Bfl = &Bs[0][0][0];

  for (int k0 = 0; k0 < IN; k0 += 32) {
    __syncthreads();
#pragma unroll
    for (int n = 0; n < 2; ++n) {
      int cA = w * 2 + n;            // chunk 0..7 (1 KB each)
      int f = cA * 64 + l;           // flat 16B-unit index: seg=f>>7, row=f&127
      const __hip_bfloat16* ga = xb + (size_t)(m0 + (f & 127)) * IN + k0 + (f >> 7) * 8;
      const __hip_bfloat16* gb = wxb + (size_t)(n0 + (f & 127)) * IN + k0 + (f >> 7) * 8;
      __builtin_amdgcn_global_load_lds((const u32*)ga, (u32*)(Af + cA * 512), 16, 0, 0);
      __builtin_amdgcn_global_load_lds((const u32*)gb, (u32*)(Bfl + cA * 512), 16, 0, 0);
    }
    __syncthreads();
    short8 a[4], b[4];
#pragma unroll
    for (int mi = 0; mi < 4; ++mi)
      a[mi] = *reinterpret_cast<const short8*>(&As[kg][wm + mi * 16 + cr][0]);
#pragma unroll
    for (int ni = 0; ni < 4; ++ni)
      b[ni] = *reinterpret_cast<const short8*>(&Bs[kg][wn + ni * 16 + cr][0]);
#pragma unroll
    for (int mi = 0; mi < 4; ++mi)
#pragma unroll
      for (int ni = 0; ni < 4; ++ni)
        acc[mi][ni] = __builtin_amdgcn_mfma_f32_16x16x32_bf16(a[mi], b[ni], acc[mi][ni], 0, 0, 0);
  }

#pragma unroll
  for (int ni = 0; ni < 4; ++ni) {
    int n = n0 + wn + ni * 16 + cr;
    float bv = bias[n];
#pragma unroll
    for (int mi = 0; mi < 4; ++mi) {
#pragma unroll
      for (int r = 0; r < 4; ++r) {
        int m = m0 + wm + mi * 16 + kg * 4 + r;
        gx[(size_t)m * NG + n] = __float2bfloat16(acc[mi][ni][r] + bv);
      }
    }
  }
}

__device__ __forceinline__ u64 ldq(const u64* p) {
  return __hip_atomic_load(p, __ATOMIC_RELAXED, __HIP_MEMORY_SCOPE_AGENT);
}
__device__ __forceinline__ void stw(u32* p, u32 v) {
  __hip_atomic_store(p, v, __ATOMIC_RELAXED, __HIP_MEMORY_SCOPE_AGENT);
}
__device__ __forceinline__ float sigm(float x) {
  return __builtin_amdgcn_rcpf(1.f + __expf(-x));
}
__device__ __forceinline__ float tanhfast(float x) {
  return 2.f * __builtin_amdgcn_rcpf(1.f + __expf(-2.f * x)) - 1.f;
}

// ---------------- persistent recurrence: tagged-dataflow h exchange ----------------
// h word = (bf16(h) << 16) | step_tag. No flags, no fences, no barriers.
// Retry is done in PARALLEL ROUNDS: each round re-issues all stale words
// concurrently (independent loads -> one L3 leg per round), never serially.
// Wh B-fragments live in REGISTERS (128 VGPRs/wave) for the whole kernel.
__global__ __launch_bounds__(256, 1) void lstm_rec(const __hip_bfloat16* __restrict__ whb,
                                                   const __hip_bfloat16* __restrict__ gx,
                                                   u32* __restrict__ hx,
                                                   float* __restrict__ out) {
  __shared__ __align__(16) float gt[4][4][16][20];
  const int tid = threadIdx.x;
  const int l = tid & 63, w = tid >> 6;
  const int jg = blockIdx.x >> 2, bg = blockIdx.x & 3;
  const int j0 = jg * 16, b0 = bg * 16;
  const int cr = l & 15, kg = l >> 4;
  const int kb0 = w * 8;
  const int bi = tid >> 4, j = tid & 15;

  // B-fragments (Wh^T) in registers: wave w holds K range [w*256, w*256+256)
  // frag element: B[k][n] = Wh[g][j0+cr][k], k = (kb0+kk)*32 + kg*8 + i
  short8 bf[8][4];
#pragma unroll
  for (int kk = 0; kk < 8; ++kk)
#pragma unroll
    for (int g = 0; g < 4; ++g)
      bf[kk][g] = *reinterpret_cast<const short8*>(
          whb + (size_t)(g * H + j0 + cr) * H + (kb0 + kk) * 32 + kg * 8);

  float c = 0.f;

  for (int t = 0; t < S; ++t) {
    const u32* hsrc = hx + (size_t)(t & 1) * (B * H);
    u32* hdst = hx + (size_t)((t + 1) & 1) * (B * H);

    const u64 tagpat = (u64)(u32)t | ((u64)(u32)t << 32);
    const u64* hp =
        reinterpret_cast<const u64*>(hsrc + (size_t)(b0 + cr) * H + w * 256 + kg * 8);

    // issue all 32 independent loads (64 h words)
    u64 q[32];
#pragma unroll
    for (int kk = 0; kk < 8; ++kk) {
#pragma unroll
      for (int x = 0; x < 4; ++x) q[kk * 4 + x] = ldq(hp + kk * 16 + x);
    }

    // gx prefetch (plain cached loads; land while we poll)
    const __hip_bfloat16* gxr = gx + (size_t)(t * B + b0 + bi) * NG + j0 + j;
    ushort q0 = *(const ushort*)&gxr[0 * H];
    ushort q1 = *(const ushort*)&gxr[1 * H];
    ushort q2 = *(const ushort*)&gxr[2 * H];
    ushort q3 = *(const ushort*)&gxr[3 * H];

    // parallel-round validation: all stale words re-issued concurrently
    bool allok;
    do {
      allok = true;
#pragma unroll
      for (int r = 0; r < 32; ++r) {
        if (((q[r] ^ tagpat) & 0x0000ffff0000ffffull) != 0ull) {
          allok = false;
          q[r] = ldq(hp + (r >> 2) * 16 + (r & 3));
        }
      }
    } while (!allok);

    // unpack (bf16 in high halves) + MFMA partials over this wave's K range
    f32x4 acc[4] = {};
#pragma unroll
    for (int kk = 0; kk < 8; ++kk) {
      u32 w0 = (u32)q[kk * 4 + 0], w1 = (u32)(q[kk * 4 + 0] >> 32);
      u32 w2 = (u32)q[kk * 4 + 1], w3 = (u32)(q[kk * 4 + 1] >> 32);
      u32 w4 = (u32)q[kk * 4 + 2], w5 = (u32)(q[kk * 4 + 2] >> 32);
      u32 w6 = (u32)q[kk * 4 + 3], w7 = (u32)(q[kk * 4 + 3] >> 32);
      union { u32 u[4]; short8 s; } ua;
      ua.u[0] = (w0 >> 16) | (w1 & 0xffff0000u);
      ua.u[1] = (w2 >> 16) | (w3 & 0xffff0000u);
      ua.u[2] = (w4 >> 16) | (w5 & 0xffff0000u);
      ua.u[3] = (w6 >> 16) | (w7 & 0xffff0000u);
#pragma unroll
      for (int g = 0; g < 4; ++g)
        acc[g] = __builtin_amdgcn_mfma_f32_16x16x32_bf16(ua.s, bf[kk][g], acc[g], 0, 0, 0);
    }
#pragma unroll
    for (int g = 0; g < 4; ++g)
      *reinterpret_cast<f32x4*>(&gt[w][g][cr][kg * 4]) = acc[g];
    __syncthreads();

    // cross-wave K reduction + gates (thread owns (batch=bi, hidden=j))
    float sf = 0.f, si = 0.f, so = 0.f, sc = 0.f;
#pragma unroll
    for (int wv = 0; wv < 4; ++wv) {
      sf += gt[wv][0][j][bi];
      si += gt[wv][1][j][bi];
      so += gt[wv][2][j][bi];
      sc += gt[wv][3][j][bi];
    }
    float gf = sf + __uint_as_float((u32)q0 << 16);
    float gi = si + __uint_as_float((u32)q1 << 16);
    float go = so + __uint_as_float((u32)q2 << 16);
    float gc = sc + __uint_as_float((u32)q3 << 16);
    float f = sigm(gf);
    float i_ = sigm(gi);
    float o = sigm(go);
    float cn = f * c + i_ * tanhfast(gc);
    float hn = o * tanhfast(cn);
    c = cn;

    out[((size_t)(t * B + b0 + bi)) * H + j0 + j] = hn;
    if (t == S - 1) {
      out[(size_t)S * B * H + (size_t)(b0 + bi) * H + j0 + j] = hn;
      out[(size_t)S * B * H + (size_t)B * H + (size_t)(b0 + bi) * H + j0 + j] = cn;
    }

    // publish h_{t+1}: one self-tagged word per thread (single L3 leg)
    u32 word = ((u32)__bfloat16_as_ushort(__float2bfloat16(hn)) << 16) | (u32)(t + 1);
    stw(hdst + (size_t)(b0 + bi) * H + j0 + j, word);

    __syncthreads();  // protect gt for next iteration's writes
  }
}

extern "C" void kernel_launch(void* const* d_in, const int* in_sizes, int n_in,
                              void* d_out, int out_size, void* d_ws, size_t ws_size,
                              hipStream_t stream) {
  const float* x = (const float*)d_in[0];
  const float* Wx[4] = {(const float*)d_in[1], (const float*)d_in[3],
                        (const float*)d_in[5], (const float*)d_in[7]};
  const float* bx[4] = {(const float*)d_in[2], (const float*)d_in[4],
                        (const float*)d_in[6], (const float*)d_in[8]};
  const float* Wh[4] = {(const float*)d_in[9], (const float*)d_in[11],
                        (const float*)d_in[13], (const float*)d_in[15]};
  const float* bh[4] = {(const float*)d_in[10], (const float*)d_in[12],
                        (const float*)d_in[14], (const float*)d_in[16]};

  char* ws = (char*)d_ws;
  size_t o_hx = 0;                                    // 2*B*H f32 = 512 KB
  size_t o_bias = o_hx + (size_t)2 * B * H * 4;
  size_t o_x = o_bias + (size_t)NG * 4;
  size_t o_wx = o_x + (size_t)M * IN * 2;
  size_t o_wh = o_wx + (size_t)NG * IN * 2;
  size_t o_gx = o_wh + (size_t)NG * H * 2;

  u32* hxp = (u32*)(ws + o_hx);
  float* biasp = (float*)(ws + o_bias);
  __hip_bfloat16* xb = (__hip_bfloat16*)(ws + o_x);
  __hip_bfloat16* wxb = (__hip_bfloat16*)(ws + o_wx);
  __hip_bfloat16* whb = (__hip_bfloat16*)(ws + o_wh);
  __hip_bfloat16* gxp = (__hip_bfloat16*)(ws + o_gx);

  // zero hx: tag 0 == step 0, value 0 == h_0 (runs inside the graph every replay)
  hipMemsetAsync(ws, 0, o_bias, stream);

  f2b<<<(M * IN / 4) / 256, 256, 0, stream>>>(x, xb, M * IN / 4);
  for (int g = 0; g < 4; ++g)
    f2b<<<(H * IN / 4) / 256, 256, 0, stream>>>(Wx[g], wxb + (size_t)g * H * IN, H * IN / 4);
  for (int g = 0; g < 4; ++g)
    f2b<<<(H * H / 4) / 256, 256, 0, stream>>>(Wh[g], whb + (size_t)g * H * H, H * H / 4);
  bias_k<<<NG / 256, 256, 0, stream>>>(bx[0], bx[1], bx[2], bx[3],
                                       bh[0], bh[1], bh[2], bh[3], biasp);

  dim3 gg(NG / 128, M / 128);
  gx_gemm<<<gg, 256, 0, stream>>>(xb, wxb, biasp, gxp);

  lstm_rec<<<256, 256, 0, stream>>>(whb, gxp, hxp, (float*)d_out);
}

// Round 6
// 1320.911 us; speedup vs baseline: 1.5858x; 1.5271x over previous
//
#include <hip/hip_runtime.h>
#include <hip/hip_bf16.h>

typedef short short8 __attribute__((ext_vector_type(8)));
typedef float f32x4 __attribute__((ext_vector_type(4)));
typedef unsigned long long u64;
typedef unsigned u32;

constexpr int S = 256, B = 64, IN = 512, H = 1024;
constexpr int M = S * B;        // 16384
constexpr int NG = 4 * H;       // 4096

// ---------------- prep: fp32 -> bf16 ----------------
__global__ void f2b(const float* __restrict__ s, __hip_bfloat16* __restrict__ d, int n4) {
  int i = blockIdx.x * blockDim.x + threadIdx.x;
  if (i >= n4) return;
  float4 v = reinterpret_cast<const float4*>(s)[i];
  __hip_bfloat16 o[4] = {__float2bfloat16(v.x), __float2bfloat16(v.y),
                         __float2bfloat16(v.z), __float2bfloat16(v.w)};
  *reinterpret_cast<uint2*>(d + 4 * (size_t)i) = *reinterpret_cast<uint2*>(o);
}

__global__ void bias_k(const float* bx0, const float* bx1, const float* bx2, const float* bx3,
                       const float* bh0, const float* bh1, const float* bh2, const float* bh3,
                       float* bias) {
  int i = blockIdx.x * blockDim.x + threadIdx.x;
  if (i >= NG) return;
  int g = i >> 10, j = i & 1023;
  const float* bx = g == 0 ? bx0 : g == 1 ? bx1 : g == 2 ? bx2 : bx3;
  const float* bh = g == 0 ? bh0 : g == 1 ? bh1 : g == 2 ? bh2 : bh3;
  bias[i] = bx[j] + bh[j];
}

// ---------------- gx = x @ Wx^T + bias : m97-structure 128x128 tile ----------------
__global__ __launch_bounds__(256) void gx_gemm(const __hip_bfloat16* __restrict__ xb,
                                               const __hip_bfloat16* __restrict__ wxb,
                                               const float* __restrict__ bias,
                                               __hip_bfloat16* __restrict__ gx) {
  __shared__ __align__(16) ushort As[4][128][8];   // 8 KB
  __shared__ __align__(16) ushort Bs[4][128][8];   // 8 KB
  const int tid = threadIdx.x;
  const int l = tid & 63, w = tid >> 6;
  const int m0 = blockIdx.y * 128, n0 = blockIdx.x * 128;
  const int wm = (w >> 1) * 64, wn = (w & 1) * 64;
  const int cr = l & 15, kg = l >> 4;
  f32x4 acc[4][4] = {};

  ushort* Af = &As[0][0][0];
  ushort* Bfl = &Bs[0][0][0];

  for (int k0 = 0; k0 < IN; k0 += 32) {
    __syncthreads();
#pragma unroll
    for (int n = 0; n < 2; ++n) {
      int cA = w * 2 + n;            // chunk 0..7 (1 KB each)
      int f = cA * 64 + l;           // flat 16B-unit index: seg=f>>7, row=f&127
      const __hip_bfloat16* ga = xb + (size_t)(m0 + (f & 127)) * IN + k0 + (f >> 7) * 8;
      const __hip_bfloat16* gb = wxb + (size_t)(n0 + (f & 127)) * IN + k0 + (f >> 7) * 8;
      __builtin_amdgcn_global_load_lds((const u32*)ga, (u32*)(Af + cA * 512), 16, 0, 0);
      __builtin_amdgcn_global_load_lds((const u32*)gb, (u32*)(Bfl + cA * 512), 16, 0, 0);
    }
    __syncthreads();
    short8 a[4], b[4];
#pragma unroll
    for (int mi = 0; mi < 4; ++mi)
      a[mi] = *reinterpret_cast<const short8*>(&As[kg][wm + mi * 16 + cr][0]);
#pragma unroll
    for (int ni = 0; ni < 4; ++ni)
      b[ni] = *reinterpret_cast<const short8*>(&Bs[kg][wn + ni * 16 + cr][0]);
#pragma unroll
    for (int mi = 0; mi < 4; ++mi)
#pragma unroll
      for (int ni = 0; ni < 4; ++ni)
        acc[mi][ni] = __builtin_amdgcn_mfma_f32_16x16x32_bf16(a[mi], b[ni], acc[mi][ni], 0, 0, 0);
  }

#pragma unroll
  for (int ni = 0; ni < 4; ++ni) {
    int n = n0 + wn + ni * 16 + cr;
    float bv = bias[n];
#pragma unroll
    for (int mi = 0; mi < 4; ++mi) {
#pragma unroll
      for (int r = 0; r < 4; ++r) {
        int m = m0 + wm + mi * 16 + kg * 4 + r;
        gx[(size_t)m * NG + n] = __float2bfloat16(acc[mi][ni][r] + bv);
      }
    }
  }
}

__device__ __forceinline__ u64 ldq(const u64* p) {
  return __hip_atomic_load(p, __ATOMIC_RELAXED, __HIP_MEMORY_SCOPE_AGENT);
}
__device__ __forceinline__ float sigm(float x) {
  return __builtin_amdgcn_rcpf(1.f + __expf(-x));
}
__device__ __forceinline__ float tanhfast(float x) {
  return 2.f * __builtin_amdgcn_rcpf(1.f + __expf(-2.f * x)) - 1.f;
}

// ---------------- persistent recurrence: flag-gated bf16 h exchange ----------------
// blockIdx = bg*64 + jg. Per step: producers store packed bf16 h (sc1 u64),
// drain vmcnt, barrier, publish ONE flag/block (sc1). Consumer wave w polls only
// its 16 producer blocks' flags (spread 64B slots), then issues 16 sc1 u64 loads.
// Wh stays in LDS (133 KB total -> hardware can only place 1 block/CU).
__global__ __launch_bounds__(256, 1) void lstm_rec(const __hip_bfloat16* __restrict__ whb,
                                                   const __hip_bfloat16* __restrict__ gx,
                                                   __hip_bfloat16* __restrict__ hx,
                                                   u32* __restrict__ flags,
                                                   float* __restrict__ out) {
  __shared__ __align__(16) ushort Bf[4][32][64][8];   // 128 KB: Wh slice, B-frag order
  __shared__ float gt[4][4][16][17];                  // 17 KB, stride 17 -> <=2-way
  const int tid = threadIdx.x;
  const int l = tid & 63, w = tid >> 6;
  const int jg = blockIdx.x & 63, bg = blockIdx.x >> 6;
  const int j0 = jg * 16, b0 = bg * 16;

  // stage Wh slice into LDS, pre-swizzled to MFMA B-fragment order (once)
  for (int idx = tid; idx < 4 * 32 * 64; idx += 256) {
    int g = idx >> 11, kb = (idx >> 6) & 31, ll = idx & 63;
    const __hip_bfloat16* src =
        whb + ((size_t)(g * H + j0 + (ll & 15))) * H + kb * 32 + (ll >> 4) * 8;
    *reinterpret_cast<uint4*>(&Bf[g][kb][ll][0]) = *reinterpret_cast<const uint4*>(src);
  }
  __syncthreads();

  const int cr = l & 15, kg = l >> 4;
  const int bi = tid >> 4, j = tid & 15;
  float c = 0.f;

  for (int t = 0; t < S; ++t) {
    const __hip_bfloat16* hsrc = hx + (size_t)(t & 1) * (B * H);
    __hip_bfloat16* hdst = hx + (size_t)((t + 1) & 1) * (B * H);

    // gx prefetch (plain cached loads; overlap the flag wait)
    const __hip_bfloat16* gxr = gx + (size_t)(t * B + b0 + bi) * NG + j0 + j;
    ushort q0 = *(const ushort*)&gxr[0 * H];
    ushort q1 = *(const ushort*)&gxr[1 * H];
    ushort q2 = *(const ushort*)&gxr[2 * H];
    ushort q3 = *(const ushort*)&gxr[3 * H];

    union { u64 q[2]; short8 s; } ua[8];
    if (t > 0) {
      // wave w needs columns [w*256, w*256+256) -> producers jg' in [w*16, w*16+16)
      const u32* fl = flags + ((size_t)t * 256 + (bg << 6) + w * 16 + (l & 15)) * 16;
      u32 fv;
      do {
        fv = __hip_atomic_load(fl, __ATOMIC_RELAXED, __HIP_MEMORY_SCOPE_AGENT);
      } while (!__all(fv != 0));
      asm volatile("" ::: "memory");

      const u64* hp =
          reinterpret_cast<const u64*>(hsrc + (size_t)(b0 + cr) * H + w * 256 + kg * 8);
#pragma unroll
      for (int kk = 0; kk < 8; ++kk) {
        ua[kk].q[0] = ldq(hp + kk * 8);
        ua[kk].q[1] = ldq(hp + kk * 8 + 1);
      }
    } else {
#pragma unroll
      for (int kk = 0; kk < 8; ++kk) { ua[kk].q[0] = 0; ua[kk].q[1] = 0; }
    }

    // MFMA partials over this wave's K range (Wh frags from LDS, 2-way = free)
    f32x4 acc[4] = {};
#pragma unroll
    for (int kk = 0; kk < 8; ++kk) {
#pragma unroll
      for (int g = 0; g < 4; ++g) {
        short8 bv = *reinterpret_cast<const short8*>(&Bf[g][w * 8 + kk][l][0]);
        acc[g] = __builtin_amdgcn_mfma_f32_16x16x32_bf16(ua[kk].s, bv, acc[g], 0, 0, 0);
      }
    }
#pragma unroll
    for (int g = 0; g < 4; ++g)
#pragma unroll
      for (int r = 0; r < 4; ++r) gt[w][g][cr][kg * 4 + r] = acc[g][r];
    __syncthreads();

    // cross-wave K reduction + gates (thread owns (batch=bi, hidden=j))
    float sf = 0.f, si = 0.f, so = 0.f, sc = 0.f;
#pragma unroll
    for (int wv = 0; wv < 4; ++wv) {
      sf += gt[wv][0][j][bi];
      si += gt[wv][1][j][bi];
      so += gt[wv][2][j][bi];
      sc += gt[wv][3][j][bi];
    }
    float gf = sf + __uint_as_float((u32)q0 << 16);
    float gi = si + __uint_as_float((u32)q1 << 16);
    float go = so + __uint_as_float((u32)q2 << 16);
    float gc = sc + __uint_as_float((u32)q3 << 16);
    float f = sigm(gf);
    float i_ = sigm(gi);
    float o = sigm(go);
    float cn = f * c + i_ * tanhfast(gc);
    float hn = o * tanhfast(cn);
    c = cn;

    out[((size_t)(t * B + b0 + bi)) * H + j0 + j] = hn;
    if (t == S - 1) {
      out[(size_t)S * B * H + (size_t)(b0 + bi) * H + j0 + j] = hn;
      out[(size_t)S * B * H + (size_t)B * H + (size_t)(b0 + bi) * H + j0 + j] = cn;
    }

    // publish h_{t+1}: pack 4 j's bf16 into one u64 (3 shfl), one sc1 store / 4 lanes
    u32 hs16 = (u32)__bfloat16_as_ushort(__float2bfloat16(hn));
    u32 p1 = (hs16 & 0xffffu) | ((u32)__shfl_xor((int)hs16, 1) << 16);
    u32 p2 = (u32)__shfl_xor((int)p1, 2);
    if (t < S - 1 && (j & 3) == 0) {
      u64 pk = (u64)p1 | ((u64)p2 << 32);
      __hip_atomic_store(reinterpret_cast<u64*>(hdst + (size_t)(b0 + bi) * H + j0 + j), pk,
                         __ATOMIC_RELAXED, __HIP_MEMORY_SCOPE_AGENT);
    }

    asm volatile("s_waitcnt vmcnt(0)" ::: "memory");  // per-wave: h stores at L3
    __syncthreads();                                  // all waves drained
    if (t < S - 1 && tid == 0)
      __hip_atomic_store(flags + ((size_t)(t + 1) * 256 + blockIdx.x) * 16, 1u,
                         __ATOMIC_RELAXED, __HIP_MEMORY_SCOPE_AGENT);
  }
}

extern "C" void kernel_launch(void* const* d_in, const int* in_sizes, int n_in,
                              void* d_out, int out_size, void* d_ws, size_t ws_size,
                              hipStream_t stream) {
  const float* x = (const float*)d_in[0];
  const float* Wx[4] = {(const float*)d_in[1], (const float*)d_in[3],
                        (const float*)d_in[5], (const float*)d_in[7]};
  const float* bx[4] = {(const float*)d_in[2], (const float*)d_in[4],
                        (const float*)d_in[6], (const float*)d_in[8]};
  const float* Wh[4] = {(const float*)d_in[9], (const float*)d_in[11],
                        (const float*)d_in[13], (const float*)d_in[15]};
  const float* bh[4] = {(const float*)d_in[10], (const float*)d_in[12],
                        (const float*)d_in[14], (const float*)d_in[16]};

  char* ws = (char*)d_ws;
  size_t o_flags = 0;                                  // S*256 slots * 64B = 4 MB
  size_t o_hx = (size_t)S * 256 * 64;
  size_t o_bias = o_hx + (size_t)2 * B * H * 2;        // hx ping-pong bf16: 256 KB
  size_t o_x = o_bias + (size_t)NG * 4;
  size_t o_wx = o_x + (size_t)M * IN * 2;
  size_t o_wh = o_wx + (size_t)NG * IN * 2;
  size_t o_gx = o_wh + (size_t)NG * H * 2;

  u32* flagsp = (u32*)(ws + o_flags);
  __hip_bfloat16* hxp = (__hip_bfloat16*)(ws + o_hx);
  float* biasp = (float*)(ws + o_bias);
  __hip_bfloat16* xb = (__hip_bfloat16*)(ws + o_x);
  __hip_bfloat16* wxb = (__hip_bfloat16*)(ws + o_wx);
  __hip_bfloat16* whb = (__hip_bfloat16*)(ws + o_wh);
  __hip_bfloat16* gxp = (__hip_bfloat16*)(ws + o_gx);

  // zero the flags each launch (h buffers need no init: t=0 skips the exchange)
  hipMemsetAsync(ws, 0, o_hx, stream);

  f2b<<<(M * IN / 4) / 256, 256, 0, stream>>>(x, xb, M * IN / 4);
  for (int g = 0; g < 4; ++g)
    f2b<<<(H * IN / 4) / 256, 256, 0, stream>>>(Wx[g], wxb + (size_t)g * H * IN, H * IN / 4);
  for (int g = 0; g < 4; ++g)
    f2b<<<(H * H / 4) / 256, 256, 0, stream>>>(Wh[g], whb + (size_t)g * H * H, H * H / 4);
  bias_k<<<NG / 256, 256, 0, stream>>>(bx[0], bx[1], bx[2], bx[3],
                                       bh[0], bh[1], bh[2], bh[3], biasp);

  dim3 gg(NG / 128, M / 128);
  gx_gemm<<<gg, 256, 0, stream>>>(xb, wxb, biasp, gxp);

  lstm_rec<<<256, 256, 0, stream>>>(whb, gxp, hxp, flagsp, (float*)d_out);
}